// Round 6
// baseline (301.447 us; speedup 1.0000x reference)
//
#include <hip/hip_runtime.h>

#define N_NODES 100000
#define N_EDGES 1600000
#define D 64
#define BN_EPS 1e-5f
#define NBKT 256
#define NPB 391                  // nodes per bucket: 256*391 = 100096 >= 100000
#define BKT_CAP 8192             // expected ~6250/bucket, sigma ~79 -> 24 sigma headroom
#define SORT_T 1024              // threads in sort_k

// ---------------------------------------------------------------------------
// Bucket pass: split edges into 256 dst-range buckets ((src,dst) int2 records).
// Bucket b covers dst in [391*b, 391*(b+1)).
// ---------------------------------------------------------------------------
__global__ __launch_bounds__(256) void bucket_k(
    const int* __restrict__ src, const int* __restrict__ dst,
    int* __restrict__ bkt_cnt, int2* __restrict__ bktbuf)
{
    __shared__ int h[NBKT], base[NBKT], cur[NBKT];
    const int t = threadIdx.x;
    if (t < NBKT) { h[t] = 0; cur[t] = 0; }
    __syncthreads();
    const int e0 = blockIdx.x * 4096;
    int s[16], d[16], b[16];
    #pragma unroll
    for (int i = 0; i < 16; ++i) {
        int e = e0 + i * 256 + t;
        if (e < N_EDGES) {
            s[i] = src[e];
            d[i] = dst[e];
            b[i] = d[i] / NPB;
            atomicAdd(&h[b[i]], 1);
        } else {
            b[i] = -1;
        }
    }
    __syncthreads();
    if (t < NBKT) base[t] = atomicAdd(&bkt_cnt[t], h[t]);
    __syncthreads();
    #pragma unroll
    for (int i = 0; i < 16; ++i) {
        if (b[i] >= 0) {
            int p = atomicAdd(&cur[b[i]], 1);
            bktbuf[(size_t)b[i] * BKT_CAP + base[b[i]] + p] = make_int2(s[i], d[i]);
        }
    }
}

// ---------------------------------------------------------------------------
// sort_k: one block per bucket (256 blocks -> full GPU). LDS counting sort
// over the bucket's 391 nodes: LDS histogram -> block scan -> coalesced
// rowptr segment -> CSR fill via LDS cursor atomics. col writes confined to
// one ~25KB region per block -> full-line writebacks in one XCD L2.
// ---------------------------------------------------------------------------
__global__ __launch_bounds__(SORT_T) void sort_k(
    const int2* __restrict__ bktbuf, const int* __restrict__ bkt_cnt,
    int* __restrict__ rowptr, int* __restrict__ col)
{
    __shared__ int h[NPB];
    __shared__ int cur[NPB];
    __shared__ int part[SORT_T];
    __shared__ int bsc[NBKT];

    const int b = blockIdx.x;
    const int t = threadIdx.x;
    const int nb0 = b * NPB;
    const int nodes_in = min(NPB, N_NODES - nb0);   // may be <=0 for trailing empty buckets
    const int cnt = bkt_cnt[b];
    const int2* buf = bktbuf + (size_t)b * BKT_CAP;

    // exclusive scan of bkt_cnt over 256 buckets -> global col base
    if (t < NBKT) bsc[t] = bkt_cnt[t];
    __syncthreads();
    for (int off = 1; off < NBKT; off <<= 1) {
        int x = 0;
        if (t < NBKT) {
            x = bsc[t];
            if (t >= off) x += bsc[t - off];
        }
        __syncthreads();
        if (t < NBKT) bsc[t] = x;
        __syncthreads();
    }
    const int gbase = bsc[b] - cnt;   // exclusive prefix

    // zero histogram
    if (t < NPB) h[t] = 0;
    __syncthreads();

    // pass 1: degree histogram (LDS atomics)
    for (int i = t; i < cnt; i += SORT_T)
        atomicAdd(&h[buf[i].y - nb0], 1);
    __syncthreads();

    // block exclusive scan over NPB entries (1 per thread, NPB < SORT_T)
    int a = (t < NPB) ? h[t] : 0;
    part[t] = a;
    __syncthreads();
    for (int off = 1; off < SORT_T; off <<= 1) {
        int x = part[t];
        int u = (t >= off) ? part[t - off] : 0;
        __syncthreads();
        part[t] = x + u;
        __syncthreads();
    }
    int excl = part[t] - a;   // exclusive prefix at t
    if (t < NPB) {
        cur[t] = excl;
        if (t < nodes_in) rowptr[nb0 + t] = gbase + excl;
    }
    if (b == NBKT - 1 && t == 0) rowptr[N_NODES] = N_EDGES;
    __syncthreads();

    // pass 2: place edges (LDS cursor atomics, one-XCD col writes)
    for (int i = t; i < cnt; i += SORT_T) {
        int2 r = buf[i];
        int slot = atomicAdd(&cur[r.y - nb0], 1);
        col[gbase + slot] = r.x;
    }
}

// ---------------------------------------------------------------------------
// Fused gather+MLP: one block per 64-node tile.
// Phase 1 (gather): each wave handles 16 nodes sequentially; lanes form 4
// groups of 16, group g takes edges lo+g, lo+g+4, ...; each lane reads a
// float4 of feat[src] (256B/edge coalesced). shfl_xor merge, add
// (1+eps)*feat self-term, write x row into xs (LDS, stride 65: 2-way banks
// = free). Phase 2: h2 = relu(x@W1+b1)@W2+b2, BN partials -> stats8.
// neigh never exists in global memory.
// ---------------------------------------------------------------------------
__global__ __launch_bounds__(256) void mlp_k(
    const float* __restrict__ feat, const int* __restrict__ rowptr,
    const int* __restrict__ col, const float* __restrict__ epsp,
    const float* __restrict__ W1, const float* __restrict__ b1,
    const float* __restrict__ W2, const float* __restrict__ b2,
    float* __restrict__ h2out, float* __restrict__ stats8)
{
    __shared__ float W1s[64 * 68];
    __shared__ float W2s[64 * 68];
    __shared__ float xs[64 * 65];
    __shared__ float b1s[64], b2s[64];

    const int t  = threadIdx.x;
    const int nb = blockIdx.x * 64;

    // stage weights (no barrier needed before gather; barrier below covers)
    #pragma unroll
    for (int i = 0; i < 4; ++i) {
        int l  = t + i * 256;
        int k  = l >> 4;
        int j4 = (l & 15) << 2;
        float4 w1 = *(const float4*)(W1 + k * 64 + j4);
        float4 w2 = *(const float4*)(W2 + k * 64 + j4);
        *(float4*)(&W1s[k * 68 + j4]) = w1;
        *(float4*)(&W2s[k * 68 + j4]) = w2;
    }
    if (t < 64)       b1s[t]      = b1[t];
    else if (t < 128) b2s[t - 64] = b2[t - 64];

    const float epsv = 1.0f + epsp[0];

    // ---- gather phase: wave wv gathers local nodes wv*16 .. wv*16+15 ----
    const int wv   = t >> 6;
    const int lane = t & 63;
    const int g    = lane >> 4;
    const int c4   = (lane & 15) << 2;

    for (int i = 0; i < 16; ++i) {
        int n  = wv * 16 + i;
        int gn = nb + n;
        float ax = 0.f, ay = 0.f, az = 0.f, aw = 0.f;
        if (gn < N_NODES) {
            int lo = rowptr[gn];
            int hi = rowptr[gn + 1];
            int e = lo + g;
            for (; e + 4 < hi; e += 8) {
                int s0 = col[e];
                int s1 = col[e + 4];
                float4 v0 = *(const float4*)(feat + (size_t)s0 * D + c4);
                float4 v1 = *(const float4*)(feat + (size_t)s1 * D + c4);
                ax += v0.x; ay += v0.y; az += v0.z; aw += v0.w;
                ax += v1.x; ay += v1.y; az += v1.z; aw += v1.w;
            }
            if (e < hi) {
                float4 v = *(const float4*)(feat + (size_t)col[e] * D + c4);
                ax += v.x; ay += v.y; az += v.z; aw += v.w;
            }
        }
        #pragma unroll
        for (int off = 16; off <= 32; off <<= 1) {
            ax += __shfl_xor(ax, off, 64);
            ay += __shfl_xor(ay, off, 64);
            az += __shfl_xor(az, off, 64);
            aw += __shfl_xor(aw, off, 64);
        }
        if (g == 0) {
            float4 f = make_float4(0.f, 0.f, 0.f, 0.f);
            if (gn < N_NODES) f = *(const float4*)(feat + (size_t)gn * D + c4);
            xs[n * 65 + c4 + 0] = fmaf(epsv, f.x, ax);
            xs[n * 65 + c4 + 1] = fmaf(epsv, f.y, ay);
            xs[n * 65 + c4 + 2] = fmaf(epsv, f.z, az);
            xs[n * 65 + c4 + 3] = fmaf(epsv, f.w, aw);
        }
    }
    __syncthreads();

    // ---- MLP phase ----
    const int n0 = (t & 15) << 2;
    const int j0 = (t >> 4) << 2;

    const float* xr0 = &xs[(n0 + 0) * 65];
    const float* xr1 = &xs[(n0 + 1) * 65];
    const float* xr2 = &xs[(n0 + 2) * 65];
    const float* xr3 = &xs[(n0 + 3) * 65];

    float acc[4][4];
    #pragma unroll
    for (int a = 0; a < 4; ++a)
        #pragma unroll
        for (int b = 0; b < 4; ++b)
            acc[a][b] = b1s[j0 + b];

    #pragma unroll 8
    for (int k = 0; k < 64; ++k) {
        const float4 w = *(const float4*)(&W1s[k * 68 + j0]);
        const float x0 = xr0[k], x1 = xr1[k], x2 = xr2[k], x3 = xr3[k];
        acc[0][0] = fmaf(x0, w.x, acc[0][0]);
        acc[0][1] = fmaf(x0, w.y, acc[0][1]);
        acc[0][2] = fmaf(x0, w.z, acc[0][2]);
        acc[0][3] = fmaf(x0, w.w, acc[0][3]);
        acc[1][0] = fmaf(x1, w.x, acc[1][0]);
        acc[1][1] = fmaf(x1, w.y, acc[1][1]);
        acc[1][2] = fmaf(x1, w.z, acc[1][2]);
        acc[1][3] = fmaf(x1, w.w, acc[1][3]);
        acc[2][0] = fmaf(x2, w.x, acc[2][0]);
        acc[2][1] = fmaf(x2, w.y, acc[2][1]);
        acc[2][2] = fmaf(x2, w.z, acc[2][2]);
        acc[2][3] = fmaf(x2, w.w, acc[2][3]);
        acc[3][0] = fmaf(x3, w.x, acc[3][0]);
        acc[3][1] = fmaf(x3, w.y, acc[3][1]);
        acc[3][2] = fmaf(x3, w.z, acc[3][2]);
        acc[3][3] = fmaf(x3, w.w, acc[3][3]);
    }

    __syncthreads();
    #pragma unroll
    for (int a = 0; a < 4; ++a)
        #pragma unroll
        for (int b = 0; b < 4; ++b)
            xs[(n0 + a) * 65 + j0 + b] = fmaxf(acc[a][b], 0.0f);
    __syncthreads();

    float acc2[4][4];
    #pragma unroll
    for (int a = 0; a < 4; ++a)
        #pragma unroll
        for (int b = 0; b < 4; ++b)
            acc2[a][b] = b2s[j0 + b];

    #pragma unroll 8
    for (int k = 0; k < 64; ++k) {
        const float4 w = *(const float4*)(&W2s[k * 68 + j0]);
        const float x0 = xr0[k], x1 = xr1[k], x2 = xr2[k], x3 = xr3[k];
        acc2[0][0] = fmaf(x0, w.x, acc2[0][0]);
        acc2[0][1] = fmaf(x0, w.y, acc2[0][1]);
        acc2[0][2] = fmaf(x0, w.z, acc2[0][2]);
        acc2[0][3] = fmaf(x0, w.w, acc2[0][3]);
        acc2[1][0] = fmaf(x1, w.x, acc2[1][0]);
        acc2[1][1] = fmaf(x1, w.y, acc2[1][1]);
        acc2[1][2] = fmaf(x1, w.z, acc2[1][2]);
        acc2[1][3] = fmaf(x1, w.w, acc2[1][3]);
        acc2[2][0] = fmaf(x2, w.x, acc2[2][0]);
        acc2[2][1] = fmaf(x2, w.y, acc2[2][1]);
        acc2[2][2] = fmaf(x2, w.z, acc2[2][2]);
        acc2[2][3] = fmaf(x2, w.w, acc2[2][3]);
        acc2[3][0] = fmaf(x3, w.x, acc2[3][0]);
        acc2[3][1] = fmaf(x3, w.y, acc2[3][1]);
        acc2[3][2] = fmaf(x3, w.z, acc2[3][2]);
        acc2[3][3] = fmaf(x3, w.w, acc2[3][3]);
    }

    float psum[4] = {0.f, 0.f, 0.f, 0.f};
    float psq[4]  = {0.f, 0.f, 0.f, 0.f};
    #pragma unroll
    for (int a = 0; a < 4; ++a) {
        int gn = nb + n0 + a;
        if (gn < N_NODES) {
            float4 hh;
            hh.x = acc2[a][0]; hh.y = acc2[a][1]; hh.z = acc2[a][2]; hh.w = acc2[a][3];
            *(float4*)(h2out + (size_t)gn * 64 + j0) = hh;
            psum[0] += hh.x; psq[0] += hh.x * hh.x;
            psum[1] += hh.y; psq[1] += hh.y * hh.y;
            psum[2] += hh.z; psq[2] += hh.z * hh.z;
            psum[3] += hh.w; psq[3] += hh.w * hh.w;
        }
    }
    #pragma unroll
    for (int off = 8; off >= 1; off >>= 1) {
        #pragma unroll
        for (int b = 0; b < 4; ++b) {
            psum[b] += __shfl_down(psum[b], off, 16);
            psq[b]  += __shfl_down(psq[b],  off, 16);
        }
    }
    if ((t & 15) == 0) {
        float* sp = stats8 + (size_t)(blockIdx.x & 7) * 128;
        #pragma unroll
        for (int b = 0; b < 4; ++b) {
            unsafeAtomicAdd(sp + j0 + b,      psum[b]);
            unsafeAtomicAdd(sp + 64 + j0 + b, psq[b]);
        }
    }
}

// ---------------------------------------------------------------------------
// K2.5: fold the 8 stat shards, produce scale/shift per column.
// ---------------------------------------------------------------------------
__global__ void bnstats_k(const float* __restrict__ stats8,
                          const float* __restrict__ gamma,
                          const float* __restrict__ beta,
                          float* __restrict__ sf)
{
    int j = threadIdx.x;  // 64 threads
    float s = 0.f, q = 0.f;
    #pragma unroll
    for (int c = 0; c < 8; ++c) {
        s += stats8[c * 128 + j];
        q += stats8[c * 128 + 64 + j];
    }
    const float invN = 1.0f / (float)N_NODES;
    float mean  = s * invN;
    float var   = q * invN - mean * mean;
    float scale = gamma[j] * rsqrtf(var + BN_EPS);
    sf[j]      = scale;
    sf[64 + j] = beta[j] - mean * scale;
}

// ---------------------------------------------------------------------------
// K3: out = relu(h2*scale + shift) + feat  (h2 lives in d_out, in-place)
// ---------------------------------------------------------------------------
__global__ __launch_bounds__(256) void finish_k(
    const float* __restrict__ feat, const float* __restrict__ sf,
    float* __restrict__ out)
{
    __shared__ float scs[64], shs[64];
    if (threadIdx.x < 64) {
        scs[threadIdx.x] = sf[threadIdx.x];
        shs[threadIdx.x] = sf[64 + threadIdx.x];
    }
    __syncthreads();
    size_t i = (size_t)blockIdx.x * 256 + threadIdx.x;   // float4 index
    if (i < (size_t)N_NODES * D / 4) {
        int j = (int)((i * 4) & 63);
        float4 h = *(float4*)(out + i * 4);
        float4 f = *(const float4*)(feat + i * 4);
        h.x = fmaxf(fmaf(h.x, scs[j + 0], shs[j + 0]), 0.f) + f.x;
        h.y = fmaxf(fmaf(h.y, scs[j + 1], shs[j + 1]), 0.f) + f.y;
        h.z = fmaxf(fmaf(h.z, scs[j + 2], shs[j + 2]), 0.f) + f.z;
        h.w = fmaxf(fmaf(h.w, scs[j + 3], shs[j + 3]), 0.f) + f.w;
        *(float4*)(out + i * 4) = h;
    }
}

extern "C" void kernel_launch(void* const* d_in, const int* in_sizes, int n_in,
                              void* d_out, int out_size, void* d_ws, size_t ws_size,
                              hipStream_t stream)
{
    const float* feat  = (const float*)d_in[0];
    const int*   src   = (const int*)d_in[1];
    const int*   dst   = (const int*)d_in[2];
    const float* eps   = (const float*)d_in[3];
    const float* W1    = (const float*)d_in[4];
    const float* b1    = (const float*)d_in[5];
    const float* W2    = (const float*)d_in[6];
    const float* b2    = (const float*)d_in[7];
    const float* gamma = (const float*)d_in[8];
    const float* beta  = (const float*)d_in[9];
    float* out = (float*)d_out;

    // workspace layout (~23.6 MB): no neigh buffer anymore.
    int2*  bktbuf  = (int2*)d_ws;                          // NBKT*BKT_CAP int2 (16.8 MB)
    int*   col     = (int*)(bktbuf + (size_t)NBKT * BKT_CAP); // N_EDGES ints
    int*   rowptr  = col + N_EDGES;                        // N_NODES+1 ints
    float* stats8  = (float*)(rowptr + N_NODES + 1);       // 8*128 floats
    int*   bkt_cnt = (int*)(stats8 + 1024);                // NBKT ints
    float* sf      = (float*)(bkt_cnt + NBKT);             // 128 floats

    // zero stats8 + bkt_cnt (contiguous, 5.1 KB)
    hipMemsetAsync(stats8, 0, 1024 * sizeof(float) + NBKT * sizeof(int), stream);

    bucket_k<<<(N_EDGES + 4095) / 4096, 256, 0, stream>>>(src, dst, bkt_cnt, bktbuf);
    sort_k<<<NBKT, SORT_T, 0, stream>>>(bktbuf, bkt_cnt, rowptr, col);
    mlp_k<<<(N_NODES + 63) / 64, 256, 0, stream>>>(feat, rowptr, col, eps, W1, b1, W2, b2, out, stats8);
    bnstats_k<<<1, 64, 0, stream>>>(stats8, gamma, beta, sf);
    finish_k<<<(N_NODES * D / 4 + 255) / 256, 256, 0, stream>>>(feat, sf, out);
}

// Round 7
// 236.609 us; speedup vs baseline: 1.2740x; 1.2740x over previous
//
#include <hip/hip_runtime.h>
#include <hip/hip_fp16.h>

#define N_NODES 100000
#define N_EDGES 1600000
#define D 64
#define BN_EPS 1e-5f
#define NBKT 256
#define NPB 391                  // nodes per bucket: 256*391 = 100096 >= 100000
#define BKT_CAP 8192             // expected ~6250/bucket, sigma ~79
#define SORT_T 1024

// ---------------------------------------------------------------------------
// Bucket pass: split edges into 256 dst-range buckets ((src,dst) int2).
// ---------------------------------------------------------------------------
__global__ __launch_bounds__(256) void bucket_k(
    const int* __restrict__ src, const int* __restrict__ dst,
    int* __restrict__ bkt_cnt, int2* __restrict__ bktbuf)
{
    __shared__ int h[NBKT], base[NBKT], cur[NBKT];
    const int t = threadIdx.x;
    if (t < NBKT) { h[t] = 0; cur[t] = 0; }
    __syncthreads();
    const int e0 = blockIdx.x * 4096;
    int s[16], d[16], b[16];
    #pragma unroll
    for (int i = 0; i < 16; ++i) {
        int e = e0 + i * 256 + t;
        if (e < N_EDGES) {
            s[i] = src[e];
            d[i] = dst[e];
            b[i] = d[i] / NPB;
            atomicAdd(&h[b[i]], 1);
        } else {
            b[i] = -1;
        }
    }
    __syncthreads();
    if (t < NBKT) base[t] = atomicAdd(&bkt_cnt[t], h[t]);
    __syncthreads();
    #pragma unroll
    for (int i = 0; i < 16; ++i) {
        if (b[i] >= 0) {
            int p = atomicAdd(&cur[b[i]], 1);
            bktbuf[(size_t)b[i] * BKT_CAP + base[b[i]] + p] = make_int2(s[i], d[i]);
        }
    }
}

// ---------------------------------------------------------------------------
// sort_k: one block per bucket. LDS counting sort -> rowptr segment + col.
// ---------------------------------------------------------------------------
__global__ __launch_bounds__(SORT_T) void sort_k(
    const int2* __restrict__ bktbuf, const int* __restrict__ bkt_cnt,
    int* __restrict__ rowptr, int* __restrict__ col)
{
    __shared__ int h[NPB];
    __shared__ int cur[NPB];
    __shared__ int part[SORT_T];
    __shared__ int bsc[NBKT];

    const int b = blockIdx.x;
    const int t = threadIdx.x;
    const int nb0 = b * NPB;
    const int nodes_in = min(NPB, N_NODES - nb0);
    const int cnt = bkt_cnt[b];
    const int2* buf = bktbuf + (size_t)b * BKT_CAP;

    if (t < NBKT) bsc[t] = bkt_cnt[t];
    __syncthreads();
    for (int off = 1; off < NBKT; off <<= 1) {
        int x = 0;
        if (t < NBKT) {
            x = bsc[t];
            if (t >= off) x += bsc[t - off];
        }
        __syncthreads();
        if (t < NBKT) bsc[t] = x;
        __syncthreads();
    }
    const int gbase = bsc[b] - cnt;

    if (t < NPB) h[t] = 0;
    __syncthreads();

    for (int i = t; i < cnt; i += SORT_T)
        atomicAdd(&h[buf[i].y - nb0], 1);
    __syncthreads();

    int a = (t < NPB) ? h[t] : 0;
    part[t] = a;
    __syncthreads();
    for (int off = 1; off < SORT_T; off <<= 1) {
        int x = part[t];
        int u = (t >= off) ? part[t - off] : 0;
        __syncthreads();
        part[t] = x + u;
        __syncthreads();
    }
    int excl = part[t] - a;
    if (t < NPB) {
        cur[t] = excl;
        if (t < nodes_in) rowptr[nb0 + t] = gbase + excl;
    }
    if (b == NBKT - 1 && t == 0) rowptr[N_NODES] = N_EDGES;
    __syncthreads();

    for (int i = t; i < cnt; i += SORT_T) {
        int2 r = buf[i];
        int slot = atomicAdd(&cur[r.y - nb0], 1);
        col[gbase + slot] = r.x;
    }
}

// ---------------------------------------------------------------------------
// conv_k: feat fp32 -> fp16 table (8 elems/thread, 16B stores).
// ---------------------------------------------------------------------------
__global__ __launch_bounds__(256) void conv_k(
    const float* __restrict__ feat, __half* __restrict__ feat16)
{
    size_t i = ((size_t)blockIdx.x * 256 + threadIdx.x) * 8;
    if (i < (size_t)N_NODES * D) {
        float4 v0 = *(const float4*)(feat + i);
        float4 v1 = *(const float4*)(feat + i + 4);
        __half2 o[4];
        o[0] = __floats2half2_rn(v0.x, v0.y);
        o[1] = __floats2half2_rn(v0.z, v0.w);
        o[2] = __floats2half2_rn(v1.x, v1.y);
        o[3] = __floats2half2_rn(v1.z, v1.w);
        *(float4*)(feat16 + i) = *(float4*)o;
    }
}

// ---------------------------------------------------------------------------
// gather16_k: one wave per node, fp16 feature rows (128B/edge). 8 groups of
// 8 lanes; group g takes edges lo+g, lo+g+8, ... Each lane loads 16B (8
// halves), fp32 accumulate, 3-step shfl_xor merge, add (1+eps)*self, store
// x row in fp16 (8 lanes x 16B).
// ---------------------------------------------------------------------------
__global__ __launch_bounds__(256) void gather16_k(
    const __half* __restrict__ feat16, const int* __restrict__ rowptr,
    const int* __restrict__ col, const float* __restrict__ epsp,
    __half* __restrict__ x16)
{
    int node = blockIdx.x * 4 + (threadIdx.x >> 6);
    int lane = threadIdx.x & 63;
    if (node >= N_NODES) return;
    int g = lane >> 3;
    int c = (lane & 7) << 3;
    int lo = rowptr[node];
    int hi = rowptr[node + 1];
    float a[8] = {0.f, 0.f, 0.f, 0.f, 0.f, 0.f, 0.f, 0.f};
    int e = lo + g;
    for (; e + 8 < hi; e += 16) {
        int s0 = col[e];
        int s1 = col[e + 8];
        float4 r0 = *(const float4*)(feat16 + (size_t)s0 * D + c);
        float4 r1 = *(const float4*)(feat16 + (size_t)s1 * D + c);
        const __half2* h0 = (const __half2*)&r0;
        const __half2* h1 = (const __half2*)&r1;
        #pragma unroll
        for (int i = 0; i < 4; ++i) {
            float2 f0 = __half22float2(h0[i]);
            float2 f1 = __half22float2(h1[i]);
            a[2 * i]     += f0.x + f1.x;
            a[2 * i + 1] += f0.y + f1.y;
        }
    }
    if (e < hi) {
        float4 r0 = *(const float4*)(feat16 + (size_t)col[e] * D + c);
        const __half2* h0 = (const __half2*)&r0;
        #pragma unroll
        for (int i = 0; i < 4; ++i) {
            float2 f0 = __half22float2(h0[i]);
            a[2 * i]     += f0.x;
            a[2 * i + 1] += f0.y;
        }
    }
    #pragma unroll
    for (int off = 8; off <= 32; off <<= 1)
        #pragma unroll
        for (int i = 0; i < 8; ++i)
            a[i] += __shfl_xor(a[i], off, 64);
    if (g == 0) {
        float4 rs = *(const float4*)(feat16 + (size_t)node * D + c);
        const __half2* hs = (const __half2*)&rs;
        const float epsv = 1.0f + epsp[0];
        __half2 o[4];
        #pragma unroll
        for (int i = 0; i < 4; ++i) {
            float2 fs = __half22float2(hs[i]);
            o[i] = __floats2half2_rn(fmaf(epsv, fs.x, a[2 * i]),
                                     fmaf(epsv, fs.y, a[2 * i + 1]));
        }
        *(float4*)(x16 + (size_t)node * D + c) = *(float4*)o;
    }
}

// ---------------------------------------------------------------------------
// gather32_k (fallback, fp32): 4 groups of 16 lanes, float4/edge-chunk.
// Writes x = (1+eps)*feat + neigh in fp32.
// ---------------------------------------------------------------------------
__global__ __launch_bounds__(256) void gather32_k(
    const float* __restrict__ feat, const int* __restrict__ rowptr,
    const int* __restrict__ col, const float* __restrict__ epsp,
    float* __restrict__ x)
{
    int node = blockIdx.x * 4 + (threadIdx.x >> 6);
    int lane = threadIdx.x & 63;
    if (node >= N_NODES) return;
    int g = lane >> 4;
    int c = (lane & 15) << 2;
    int lo = rowptr[node];
    int hi = rowptr[node + 1];
    float ax = 0.f, ay = 0.f, az = 0.f, aw = 0.f;
    int e = lo + g;
    for (; e + 4 < hi; e += 8) {
        int s0 = col[e];
        int s1 = col[e + 4];
        float4 v0 = *(const float4*)(feat + (size_t)s0 * D + c);
        float4 v1 = *(const float4*)(feat + (size_t)s1 * D + c);
        ax += v0.x; ay += v0.y; az += v0.z; aw += v0.w;
        ax += v1.x; ay += v1.y; az += v1.z; aw += v1.w;
    }
    if (e < hi) {
        float4 v = *(const float4*)(feat + (size_t)col[e] * D + c);
        ax += v.x; ay += v.y; az += v.z; aw += v.w;
    }
    #pragma unroll
    for (int off = 16; off <= 32; off <<= 1) {
        ax += __shfl_xor(ax, off, 64);
        ay += __shfl_xor(ay, off, 64);
        az += __shfl_xor(az, off, 64);
        aw += __shfl_xor(aw, off, 64);
    }
    if (g == 0) {
        float4 f = *(const float4*)(feat + (size_t)node * D + c);
        const float epsv = 1.0f + epsp[0];
        float4 r;
        r.x = fmaf(epsv, f.x, ax);
        r.y = fmaf(epsv, f.y, ay);
        r.z = fmaf(epsv, f.z, az);
        r.w = fmaf(epsv, f.w, aw);
        *(float4*)(x + (size_t)node * D + c) = r;
    }
}

// ---------------------------------------------------------------------------
// staging load helpers: 8 consecutive elems -> fp32
// ---------------------------------------------------------------------------
__device__ inline void ld8(const float* p, float* o) {
    float4 a = *(const float4*)p;
    float4 b = *(const float4*)(p + 4);
    o[0] = a.x; o[1] = a.y; o[2] = a.z; o[3] = a.w;
    o[4] = b.x; o[5] = b.y; o[6] = b.z; o[7] = b.w;
}
__device__ inline void ld8(const __half* p, float* o) {
    float4 raw = *(const float4*)p;
    const __half2* h = (const __half2*)&raw;
    #pragma unroll
    for (int i = 0; i < 4; ++i) {
        float2 f = __half22float2(h[i]);
        o[2 * i] = f.x; o[2 * i + 1] = f.y;
    }
}

// ---------------------------------------------------------------------------
// mlp_k<XT>: per 64-node tile, x pre-assembled ((1+eps)*feat + neigh).
// h2 = relu(x@W1+b1)@W2+b2 -> h2out; BN partials -> stats8.
// ---------------------------------------------------------------------------
template <typename XT>
__global__ __launch_bounds__(256) void mlp_k(
    const XT* __restrict__ x,
    const float* __restrict__ W1, const float* __restrict__ b1,
    const float* __restrict__ W2, const float* __restrict__ b2,
    float* __restrict__ h2out, float* __restrict__ stats8)
{
    __shared__ float W1s[64 * 68];
    __shared__ float W2s[64 * 68];
    __shared__ float xs[64 * 65];
    __shared__ float b1s[64], b2s[64];

    const int t  = threadIdx.x;
    const int nb = blockIdx.x * 64;

    #pragma unroll
    for (int i = 0; i < 4; ++i) {
        int l  = t + i * 256;
        int k  = l >> 4;
        int j4 = (l & 15) << 2;
        float4 w1 = *(const float4*)(W1 + k * 64 + j4);
        float4 w2 = *(const float4*)(W2 + k * 64 + j4);
        *(float4*)(&W1s[k * 68 + j4]) = w1;
        *(float4*)(&W2s[k * 68 + j4]) = w2;
    }
    if (t < 64)       b1s[t]      = b1[t];
    else if (t < 128) b2s[t - 64] = b2[t - 64];

    // stage x rows: 2 iters x 8 cols per thread
    #pragma unroll
    for (int i = 0; i < 2; ++i) {
        int n  = (t >> 3) + i * 32;
        int k8 = (t & 7) << 3;
        int gn = nb + n;
        float v[8] = {0.f, 0.f, 0.f, 0.f, 0.f, 0.f, 0.f, 0.f};
        if (gn < N_NODES) ld8(x + (size_t)gn * D + k8, v);
        #pragma unroll
        for (int j = 0; j < 8; ++j) xs[n * 65 + k8 + j] = v[j];
    }
    __syncthreads();

    const int n0 = (t & 15) << 2;
    const int j0 = (t >> 4) << 2;

    const float* xr0 = &xs[(n0 + 0) * 65];
    const float* xr1 = &xs[(n0 + 1) * 65];
    const float* xr2 = &xs[(n0 + 2) * 65];
    const float* xr3 = &xs[(n0 + 3) * 65];

    float acc[4][4];
    #pragma unroll
    for (int a = 0; a < 4; ++a)
        #pragma unroll
        for (int b = 0; b < 4; ++b)
            acc[a][b] = b1s[j0 + b];

    #pragma unroll 8
    for (int k = 0; k < 64; ++k) {
        const float4 w = *(const float4*)(&W1s[k * 68 + j0]);
        const float x0 = xr0[k], x1 = xr1[k], x2 = xr2[k], x3 = xr3[k];
        acc[0][0] = fmaf(x0, w.x, acc[0][0]);
        acc[0][1] = fmaf(x0, w.y, acc[0][1]);
        acc[0][2] = fmaf(x0, w.z, acc[0][2]);
        acc[0][3] = fmaf(x0, w.w, acc[0][3]);
        acc[1][0] = fmaf(x1, w.x, acc[1][0]);
        acc[1][1] = fmaf(x1, w.y, acc[1][1]);
        acc[1][2] = fmaf(x1, w.z, acc[1][2]);
        acc[1][3] = fmaf(x1, w.w, acc[1][3]);
        acc[2][0] = fmaf(x2, w.x, acc[2][0]);
        acc[2][1] = fmaf(x2, w.y, acc[2][1]);
        acc[2][2] = fmaf(x2, w.z, acc[2][2]);
        acc[2][3] = fmaf(x2, w.w, acc[2][3]);
        acc[3][0] = fmaf(x3, w.x, acc[3][0]);
        acc[3][1] = fmaf(x3, w.y, acc[3][1]);
        acc[3][2] = fmaf(x3, w.z, acc[3][2]);
        acc[3][3] = fmaf(x3, w.w, acc[3][3]);
    }

    __syncthreads();
    #pragma unroll
    for (int a = 0; a < 4; ++a)
        #pragma unroll
        for (int b = 0; b < 4; ++b)
            xs[(n0 + a) * 65 + j0 + b] = fmaxf(acc[a][b], 0.0f);
    __syncthreads();

    float acc2[4][4];
    #pragma unroll
    for (int a = 0; a < 4; ++a)
        #pragma unroll
        for (int b = 0; b < 4; ++b)
            acc2[a][b] = b2s[j0 + b];

    #pragma unroll 8
    for (int k = 0; k < 64; ++k) {
        const float4 w = *(const float4*)(&W2s[k * 68 + j0]);
        const float x0 = xr0[k], x1 = xr1[k], x2 = xr2[k], x3 = xr3[k];
        acc2[0][0] = fmaf(x0, w.x, acc2[0][0]);
        acc2[0][1] = fmaf(x0, w.y, acc2[0][1]);
        acc2[0][2] = fmaf(x0, w.z, acc2[0][2]);
        acc2[0][3] = fmaf(x0, w.w, acc2[0][3]);
        acc2[1][0] = fmaf(x1, w.x, acc2[1][0]);
        acc2[1][1] = fmaf(x1, w.y, acc2[1][1]);
        acc2[1][2] = fmaf(x1, w.z, acc2[1][2]);
        acc2[1][3] = fmaf(x1, w.w, acc2[1][3]);
        acc2[2][0] = fmaf(x2, w.x, acc2[2][0]);
        acc2[2][1] = fmaf(x2, w.y, acc2[2][1]);
        acc2[2][2] = fmaf(x2, w.z, acc2[2][2]);
        acc2[2][3] = fmaf(x2, w.w, acc2[2][3]);
        acc2[3][0] = fmaf(x3, w.x, acc2[3][0]);
        acc2[3][1] = fmaf(x3, w.y, acc2[3][1]);
        acc2[3][2] = fmaf(x3, w.z, acc2[3][2]);
        acc2[3][3] = fmaf(x3, w.w, acc2[3][3]);
    }

    float psum[4] = {0.f, 0.f, 0.f, 0.f};
    float psq[4]  = {0.f, 0.f, 0.f, 0.f};
    #pragma unroll
    for (int a = 0; a < 4; ++a) {
        int gn = nb + n0 + a;
        if (gn < N_NODES) {
            float4 hh;
            hh.x = acc2[a][0]; hh.y = acc2[a][1]; hh.z = acc2[a][2]; hh.w = acc2[a][3];
            *(float4*)(h2out + (size_t)gn * 64 + j0) = hh;
            psum[0] += hh.x; psq[0] += hh.x * hh.x;
            psum[1] += hh.y; psq[1] += hh.y * hh.y;
            psum[2] += hh.z; psq[2] += hh.z * hh.z;
            psum[3] += hh.w; psq[3] += hh.w * hh.w;
        }
    }
    #pragma unroll
    for (int off = 8; off >= 1; off >>= 1) {
        #pragma unroll
        for (int b = 0; b < 4; ++b) {
            psum[b] += __shfl_down(psum[b], off, 16);
            psq[b]  += __shfl_down(psq[b],  off, 16);
        }
    }
    if ((t & 15) == 0) {
        float* sp = stats8 + (size_t)(blockIdx.x & 7) * 128;
        #pragma unroll
        for (int b = 0; b < 4; ++b) {
            unsafeAtomicAdd(sp + j0 + b,      psum[b]);
            unsafeAtomicAdd(sp + 64 + j0 + b, psq[b]);
        }
    }
}

// ---------------------------------------------------------------------------
// bnstats_k: fold 8 stat shards -> scale/shift.
// ---------------------------------------------------------------------------
__global__ void bnstats_k(const float* __restrict__ stats8,
                          const float* __restrict__ gamma,
                          const float* __restrict__ beta,
                          float* __restrict__ sf)
{
    int j = threadIdx.x;
    float s = 0.f, q = 0.f;
    #pragma unroll
    for (int c = 0; c < 8; ++c) {
        s += stats8[c * 128 + j];
        q += stats8[c * 128 + 64 + j];
    }
    const float invN = 1.0f / (float)N_NODES;
    float mean  = s * invN;
    float var   = q * invN - mean * mean;
    float scale = gamma[j] * rsqrtf(var + BN_EPS);
    sf[j]      = scale;
    sf[64 + j] = beta[j] - mean * scale;
}

// ---------------------------------------------------------------------------
// finish_k: out = relu(h2*scale + shift) + feat (in-place on d_out).
// ---------------------------------------------------------------------------
__global__ __launch_bounds__(256) void finish_k(
    const float* __restrict__ feat, const float* __restrict__ sf,
    float* __restrict__ out)
{
    __shared__ float scs[64], shs[64];
    if (threadIdx.x < 64) {
        scs[threadIdx.x] = sf[threadIdx.x];
        shs[threadIdx.x] = sf[64 + threadIdx.x];
    }
    __syncthreads();
    size_t i = (size_t)blockIdx.x * 256 + threadIdx.x;
    if (i < (size_t)N_NODES * D / 4) {
        int j = (int)((i * 4) & 63);
        float4 h = *(float4*)(out + i * 4);
        float4 f = *(const float4*)(feat + i * 4);
        h.x = fmaxf(fmaf(h.x, scs[j + 0], shs[j + 0]), 0.f) + f.x;
        h.y = fmaxf(fmaf(h.y, scs[j + 1], shs[j + 1]), 0.f) + f.y;
        h.z = fmaxf(fmaf(h.z, scs[j + 2], shs[j + 2]), 0.f) + f.z;
        h.w = fmaxf(fmaf(h.w, scs[j + 3], shs[j + 3]), 0.f) + f.w;
        *(float4*)(out + i * 4) = h;
    }
}

extern "C" void kernel_launch(void* const* d_in, const int* in_sizes, int n_in,
                              void* d_out, int out_size, void* d_ws, size_t ws_size,
                              hipStream_t stream)
{
    const float* feat  = (const float*)d_in[0];
    const int*   src   = (const int*)d_in[1];
    const int*   dst   = (const int*)d_in[2];
    const float* eps   = (const float*)d_in[3];
    const float* W1    = (const float*)d_in[4];
    const float* b1    = (const float*)d_in[5];
    const float* W2    = (const float*)d_in[6];
    const float* b2    = (const float*)d_in[7];
    const float* gamma = (const float*)d_in[8];
    const float* beta  = (const float*)d_in[9];
    float* out = (float*)d_out;

    const size_t BKTSZ = (size_t)NBKT * BKT_CAP * sizeof(int2);   // 16.78 MB
    const size_t F16SZ = (size_t)N_NODES * D * sizeof(__half);    // 12.8 MB
    const size_t X32SZ = (size_t)N_NODES * D * sizeof(float);     // 25.6 MB
    const size_t COLSZ = (size_t)N_EDGES * sizeof(int);
    const size_t RPSZ  = (size_t)(N_NODES + 1) * sizeof(int);
    const size_t TAIL  = 1024 * 4 + NBKT * 4 + 128 * 4;
    const size_t need16 = BKTSZ + F16SZ + COLSZ + RPSZ + TAIL;    // ~36.4 MB

    if (ws_size >= need16) {
        // fp16 gather path. x16 aliases bktbuf (sort done before gather).
        char* p = (char*)d_ws;
        __half* x16    = (__half*)p;
        int2*   bktbuf = (int2*)p;
        __half* feat16 = (__half*)(p + BKTSZ);
        int*    col    = (int*)(p + BKTSZ + F16SZ);
        int*    rowptr = col + N_EDGES;
        float*  stats8 = (float*)(rowptr + N_NODES + 1);
        int*    bkt_cnt = (int*)(stats8 + 1024);
        float*  sf     = (float*)(bkt_cnt + NBKT);

        hipMemsetAsync(stats8, 0, 1024 * 4 + NBKT * 4, stream);
        conv_k<<<3125, 256, 0, stream>>>(feat, feat16);
        bucket_k<<<(N_EDGES + 4095) / 4096, 256, 0, stream>>>(src, dst, bkt_cnt, bktbuf);
        sort_k<<<NBKT, SORT_T, 0, stream>>>(bktbuf, bkt_cnt, rowptr, col);
        gather16_k<<<(N_NODES + 3) / 4, 256, 0, stream>>>(feat16, rowptr, col, eps, x16);
        mlp_k<__half><<<(N_NODES + 63) / 64, 256, 0, stream>>>(x16, W1, b1, W2, b2, out, stats8);
        bnstats_k<<<1, 64, 0, stream>>>(stats8, gamma, beta, sf);
        finish_k<<<(N_NODES * D / 4 + 255) / 256, 256, 0, stream>>>(feat, sf, out);
    } else {
        // fp32 fallback (proven 32.4 MB layout). x32 aliases bktbuf.
        char* p = (char*)d_ws;
        float* x32    = (float*)p;
        int2*  bktbuf = (int2*)p;
        int*   col    = (int*)(p + X32SZ);
        int*   rowptr = col + N_EDGES;
        float* stats8 = (float*)(rowptr + N_NODES + 1);
        int*   bkt_cnt = (int*)(stats8 + 1024);
        float* sf     = (float*)(bkt_cnt + NBKT);

        hipMemsetAsync(stats8, 0, 1024 * 4 + NBKT * 4, stream);
        bucket_k<<<(N_EDGES + 4095) / 4096, 256, 0, stream>>>(src, dst, bkt_cnt, bktbuf);
        sort_k<<<NBKT, SORT_T, 0, stream>>>(bktbuf, bkt_cnt, rowptr, col);
        gather32_k<<<(N_NODES + 3) / 4, 256, 0, stream>>>(feat, rowptr, col, eps, x32);
        mlp_k<float><<<(N_NODES + 63) / 64, 256, 0, stream>>>(x32, W1, b1, W2, b2, out, stats8);
        bnstats_k<<<1, 64, 0, stream>>>(stats8, gamma, beta, sf);
        finish_k<<<(N_NODES * D / 4 + 255) / 256, 256, 0, stream>>>(feat, sf, out);
    }
}